// Round 20
// baseline (85.040 us; speedup 1.0000x reference)
//
#include <hip/hip_runtime.h>
#include <hip/hip_bf16.h>

// Problem constants
#define BB 64
#define NN 500
#define CC 256
#define HH 64
#define WW 64
#define HWSZ 4096
#define NPTS 32000
#define NPAD 512

typedef __attribute__((ext_vector_type(4))) short s4v;
typedef __attribute__((ext_vector_type(8))) short s8v;
typedef __attribute__((ext_vector_type(4))) float f4v;
typedef __attribute__((ext_vector_type(4))) int i4v;

// RNE round f32 -> bf16 (ushort)
__device__ __forceinline__ unsigned short bfround(float f) {
    unsigned u = __builtin_bit_cast(unsigned, f);
    return (unsigned short)((u + 0x7FFFu + ((u >> 16) & 1u)) >> 16);
}

__device__ __forceinline__ void prep_point(const float* __restrict__ pts,
                                           int b, int n, int4& id, float4& wt) {
    float x = (pts[((size_t)b * NN + n) * 2 + 0] + 1.f) * 0.5f * (float)(WW - 1);
    float y = (pts[((size_t)b * NN + n) * 2 + 1] + 1.f) * 0.5f * (float)(HH - 1);
    float x0f = floorf(x), y0f = floorf(y);
    float x1f = x0f + 1.f, y1f = y0f + 1.f;
    float wx1 = x - x0f, wx0 = 1.f - wx1;
    float wy1 = y - y0f, wy0 = 1.f - wy1;
    float mx0 = (x0f >= 0.f && x0f <= (float)(WW - 1)) ? 1.f : 0.f;
    float mx1 = (x1f >= 0.f && x1f <= (float)(WW - 1)) ? 1.f : 0.f;
    float my0 = (y0f >= 0.f && y0f <= (float)(HH - 1)) ? 1.f : 0.f;
    float my1 = (y1f >= 0.f && y1f <= (float)(HH - 1)) ? 1.f : 0.f;
    int x0 = (int)fminf(fmaxf(x0f, 0.f), (float)(WW - 1));
    int x1 = (int)fminf(fmaxf(x1f, 0.f), (float)(WW - 1));
    int y0 = (int)fminf(fmaxf(y0f, 0.f), (float)(HH - 1));
    int y1 = (int)fminf(fmaxf(y1f, 0.f), (float)(HH - 1));
    id = make_int4(y0 * WW + x0, y0 * WW + x1, y1 * WW + x0, y1 * WW + x1);
    wt = make_float4(wx0 * wy0 * mx0 * my0, wx1 * wy0 * mx1 * my0,
                     wx0 * wy1 * mx0 * my1, wx1 * wy1 * mx1 * my1);
}

// ---------------------------------------------------------------------------
// K1: gather + pack + fcwT transpose, 256 threads/block.
//  Gather: 32 KB LDS (2x16KB dbuf) -> 5 blocks/CU = 5 independent DMA
//  streams (vs 3 at r19's 48 KB). Each thread gathers 2 points (n, n+256).
//  featB layout unchanged: [b][kg][jp][n] paired-channel uint.
// ---------------------------------------------------------------------------
#define GATHER_BLKS 2048
#define NCHB 8
#define W0F_N 32768   // 8 Mt * 8 s * 512
#define W1F_N 24576   // 4 Mt * 12 s * 512
#define W2F_N 5120    // 1 Mt * 10 s * 512
#define PACK_N (W0F_N + W1F_N + W2F_N)
#define PACK_BLKS ((PACK_N + 255) / 256)      // 244
#define TR_BLKS (40 * 4)                      // 2500/64 x 236/64 tiles
#define TOTAL_BLKS (GATHER_BLKS + PACK_BLKS + TR_BLKS)

__global__ __launch_bounds__(256) void k_gp(const float* __restrict__ sfeat,
                                            const float* __restrict__ pts,
                                            const float* __restrict__ w0,
                                            const float* __restrict__ w1,
                                            const float* __restrict__ w2,
                                            const float* __restrict__ fcw,
                                            unsigned int* __restrict__ featB,
                                            unsigned short* __restrict__ w0f,
                                            unsigned short* __restrict__ w1f,
                                            unsigned short* __restrict__ w2f,
                                            float* __restrict__ fcwT) {
    __shared__ float im[2][HWSZ];   // 32 KB -> 5 blocks/CU
    const int blk = blockIdx.x;
    const int tid = threadIdx.x;

    if (blk >= GATHER_BLKS + PACK_BLKS) {
        // ---- fcwT tiled transpose: 64k x 64o tiles, LDS reuses im ----
        float (*tile)[65] = (float(*)[65])im;  // 16.6 KB < 32 KB
        const int tb = blk - (GATHER_BLKS + PACK_BLKS);
        const int kt = tb % 40, ot = tb / 40;
        const int k0 = kt * 64, o0 = ot * 64;
        for (int i = tid; i < 64 * 64; i += 256) {
            int oo = i >> 6, kk = i & 63;
            int o = o0 + oo, k = k0 + kk;
            tile[oo][kk] = (o < 236 && k < 2500) ? fcw[(size_t)o * 2500 + k] : 0.f;
        }
        __syncthreads();
        for (int i = tid; i < 64 * 64; i += 256) {
            int kk = i >> 6, oo = i & 63;
            int o = o0 + oo, k = k0 + kk;
            if (o < 236 && k < 2500) fcwT[(size_t)k * 236 + o] = tile[oo][kk];
        }
        return;
    }

    if (blk >= GATHER_BLKS) {
        // ---- weight-frag pack (r7-verified k-labeling) ----
        int i = (blk - GATHER_BLKS) * 256 + tid;
        if (i < W0F_N) {
            int j = i & 7, ll = (i >> 3) & 63, s = (i >> 9) & 7, m = i >> 12;
            int row = m * 16 + (ll & 15), k = s * 32 + (ll >> 4) * 8 + j;
            w0f[i] = bfround(w0[row * 256 + k]);
        } else if (i < W0F_N + W1F_N) {
            int d = i - W0F_N;
            int j = d & 7, ll = (d >> 3) & 63, rest = d >> 9;
            int s = rest % 12, m = rest / 12;
            int row = m * 16 + (ll & 15), k = s * 32 + (ll >> 4) * 8 + j;
            w1f[d] = bfround(w1[row * 384 + k]);
        } else if (i < PACK_N) {
            int d = i - (W0F_N + W1F_N);
            int j = d & 7, ll = (d >> 3) & 63, s = d >> 9;
            int row = ll & 15, k = s * 32 + (ll >> 4) * 8 + j;
            float v = (row < 5) ? w2[row * 320 + k] : 0.f;
            w2f[d] = bfround(v);
        }
        return;
    }

    // ---- gather path ----
    const int b     = blk >> 5;          // 32 chunks per batch
    const int chunk = blk & 31;
    const int ch0   = chunk * NCHB;
    const int n0p   = tid;               // point 0: always < 500
    const int n1p   = tid + 256;         // point 1: valid if < 500

    int4 id0, id1 = make_int4(0, 0, 0, 0);
    float4 wt0, wt1 = make_float4(0.f, 0.f, 0.f, 0.f);
    prep_point(pts, b, n0p, id0, wt0);
    if (n1p < NN) prep_point(pts, b, n1p, id1, wt1);

    const float4* src = (const float4*)(sfeat + ((size_t)b * CC + ch0) * HWSZ);

#define ISSUE_CH(T, BUF)                                                      \
    {                                                                         \
        const float4* s2 = src + (size_t)(T) * (HWSZ / 4);                    \
        float4* dst = (float4*)im[BUF];                                       \
        _Pragma("unroll")                                                     \
        for (int it = 0; it < 4; it++) {                                      \
            int j = it * 256 + tid;                                           \
            __builtin_amdgcn_global_load_lds(                                 \
                (const __attribute__((address_space(1))) void*)(s2 + j),      \
                (__attribute__((address_space(3))) void*)(dst + j),           \
                16, 0, 0);                                                    \
        }                                                                     \
    }

    ISSUE_CH(0, 0);

    unsigned short hprev0 = 0, hprev1 = 0;
    for (int t = 0; t < NCHB; t++) {
        if (t + 1 < NCHB) {
            ISSUE_CH(t + 1, (t + 1) & 1);
            asm volatile("s_waitcnt vmcnt(4)" ::: "memory");  // ch t landed
        } else {
            asm volatile("s_waitcnt vmcnt(0)" ::: "memory");
        }
        asm volatile("s_barrier" ::: "memory");

        const float* L = im[t & 1];
        float r0 = wt0.x * L[id0.x] + wt0.y * L[id0.y] +
                   wt0.z * L[id0.z] + wt0.w * L[id0.w];
        unsigned short h0 = bfround(r0);
        unsigned short h1 = 0;
        if (n1p < NN) {
            float r1 = wt1.x * L[id1.x] + wt1.y * L[id1.y] +
                       wt1.z * L[id1.z] + wt1.w * L[id1.w];
            h1 = bfround(r1);
        }
        if (t & 1) {
            size_t base = (((size_t)b * 32 + chunk) * 4 + (t >> 1)) * 512;
            featB[base + n0p] = (unsigned int)hprev0 | ((unsigned int)h0 << 16);
            if (n1p < NN)
                featB[base + n1p] = (unsigned int)hprev1 | ((unsigned int)h1 << 16);
        } else {
            hprev0 = h0; hprev1 = h1;
        }
        if (t + 1 < NCHB)
            asm volatile("s_barrier" ::: "memory");  // frees im[t&1] for reuse
    }
#undef ISSUE_CH
}

// ---------------------------------------------------------------------------
// K2: plain-bf16 MFMA fused MLP, TILE=64 (byte-identical to r19).
// ---------------------------------------------------------------------------
#define K1_S 136
#define K2_S 72

__device__ __forceinline__ s8v mkfrag(const unsigned short* p) {
    return *(const s8v*)p;
}

__global__ __launch_bounds__(512, 4) void k_mlp(const unsigned int* __restrict__ featB,
                                                const unsigned short* __restrict__ w0f,
                                                const unsigned short* __restrict__ w1f,
                                                const unsigned short* __restrict__ w2f,
                                                const float* __restrict__ b0,
                                                const float* __restrict__ b1,
                                                const float* __restrict__ b2,
                                                float* __restrict__ y2f) {
    __shared__ unsigned short c1B[64 * K1_S];
    __shared__ unsigned short c2B[64 * K2_S];   // total 26,624 B

    const int b   = blockIdx.y;
    const int n0  = blockIdx.x * 64;
    const int tid = threadIdx.x;
    const int w   = tid >> 6, l = tid & 63;
    const int nt  = w & 3, mh = w >> 2;
    const int lo16 = l & 15, hi = l >> 4;
    const int c = nt * 16 + lo16;          // point column 0..63

    // ---- B-fragments: 32 x 4B coalesced loads ----
    s8v bhs[8];
    const unsigned int* fb = featB + (size_t)b * (32 * 4 * 512) + (n0 + c);
#pragma unroll
    for (int s = 0; s < 8; s++) {
        const int kg = s * 4 + hi;
        i4v hx;
#pragma unroll
        for (int t = 0; t < 4; t++)
            hx[t] = (int)fb[(size_t)(kg * 4 + t) * 512];
        bhs[s] = __builtin_bit_cast(s8v, hx);
    }

    // ---- layer 0: 128 outs (8 Mt), K=256; wave does Mt = mh*4 + q ----
    f4v acc[4];
#pragma unroll
    for (int q = 0; q < 4; q++) acc[q] = (f4v){0.f, 0.f, 0.f, 0.f};
#pragma unroll
    for (int s = 0; s < 8; s++) {
#pragma unroll
        for (int q = 0; q < 4; q++) {
            const s8v a = mkfrag(w0f + ((size_t)((mh * 4 + q) * 8 + s) * 64 + l) * 8);
            acc[q] = __builtin_amdgcn_mfma_f32_16x16x32_bf16(a, bhs[s], acc[q], 0, 0, 0);
        }
    }
#pragma unroll
    for (int q = 0; q < 4; q++) {
#pragma unroll
        for (int r = 0; r < 4; r++) {
            int ch = (mh * 4 + q) * 16 + hi * 4 + r;
            float v = acc[q][r] + b0[ch];
            v = v > 0.f ? v : 0.01f * v;
            c1B[c * K1_S + ch] = bfround(v);
        }
    }
    __syncthreads();

    // ---- layer 1: 64 outs (4 Mt), K=128(c1)+256(feat); Mt = mh*2 + q ----
    f4v accA[2];
#pragma unroll
    for (int q = 0; q < 2; q++) accA[q] = (f4v){0.f, 0.f, 0.f, 0.f};
#pragma unroll
    for (int s = 0; s < 4; s++) {
        const s8v bh = *(const s8v*)&c1B[c * K1_S + s * 32 + hi * 8];
#pragma unroll
        for (int q = 0; q < 2; q++) {
            const s8v a = mkfrag(w1f + ((size_t)((mh * 2 + q) * 12 + s) * 64 + l) * 8);
            accA[q] = __builtin_amdgcn_mfma_f32_16x16x32_bf16(a, bh, accA[q], 0, 0, 0);
        }
    }
#pragma unroll
    for (int s = 4; s < 12; s++) {
#pragma unroll
        for (int q = 0; q < 2; q++) {
            const s8v a = mkfrag(w1f + ((size_t)((mh * 2 + q) * 12 + s) * 64 + l) * 8);
            accA[q] = __builtin_amdgcn_mfma_f32_16x16x32_bf16(a, bhs[s - 4], accA[q], 0, 0, 0);
        }
    }
#pragma unroll
    for (int q = 0; q < 2; q++) {
#pragma unroll
        for (int r = 0; r < 4; r++) {
            int ch = (mh * 2 + q) * 16 + hi * 4 + r;
            float v = accA[q][r] + b1[ch];
            v = v > 0.f ? v : 0.01f * v;
            c2B[c * K2_S + ch] = bfround(v);
        }
    }
    __syncthreads();

    // ---- layer 2: 5 outs (1 Mt), K=64(c2)+256(feat); waves mh==0 ----
    if (mh == 0) {
        f4v acc2 = {0.f, 0.f, 0.f, 0.f};
#pragma unroll
        for (int s = 0; s < 2; s++) {
            const s8v bh = *(const s8v*)&c2B[c * K2_S + s * 32 + hi * 8];
            const s8v a  = mkfrag(w2f + ((size_t)s * 64 + l) * 8);
            acc2 = __builtin_amdgcn_mfma_f32_16x16x32_bf16(a, bh, acc2, 0, 0, 0);
        }
#pragma unroll
        for (int s = 2; s < 10; s++) {
            const s8v a = mkfrag(w2f + ((size_t)s * 64 + l) * 8);
            acc2 = __builtin_amdgcn_mfma_f32_16x16x32_bf16(a, bhs[s - 2], acc2, 0, 0, 0);
        }
#pragma unroll
        for (int r = 0; r < 4; r++) {
            int ch = hi * 4 + r;
            if (ch < 5) {
                float v = acc2[r] + b2[ch];
                v = fmaxf(v, 0.f);
                int n = n0 + c;
                if (n < NN) y2f[(size_t)b * 2500 + ch * NN + n] = v;
            }
        }
    }
}

// ---------------------------------------------------------------------------
// K3: FC two-stage (r15/r19-identical). FC needs BOTH: k-split TLP AND
// coalesced weight reads (r10/r16 each violated one -> 170-200us).
// ---------------------------------------------------------------------------
__global__ __launch_bounds__(256) void k_fc1(const float* __restrict__ y2f,
                                             const float* __restrict__ fcwT,
                                             float* __restrict__ part) {
    __shared__ float ys[313];
    const int b  = blockIdx.x & 63;
    const int kc = blockIdx.x >> 6;
    const int start = kc * 312 + (kc < 4 ? kc : 4);
    const int len   = (kc < 4) ? 313 : 312;
    const float* yb = y2f + (size_t)b * 2500 + start;
    for (int j = threadIdx.x; j < len; j += 256) ys[j] = yb[j];
    __syncthreads();
    const int o = threadIdx.x;
    if (o < 236) {
        float acc = 0.f;
        const float* wp = fcwT + (size_t)start * 236 + o;
#pragma unroll 8
        for (int k = 0; k < len; k++) acc = fmaf(wp[(size_t)k * 236], ys[k], acc);
        part[((size_t)kc * 64 + b) * 236 + o] = acc;
    }
}

__global__ __launch_bounds__(256) void k_fc2(const float* __restrict__ part,
                                             const float* __restrict__ fcb,
                                             float* __restrict__ out) {
    const int b = blockIdx.x;
    const int o = threadIdx.x;
    if (o < 236) {
        float acc = fcb[o];
#pragma unroll
        for (int kc = 0; kc < 8; kc++) acc += part[((size_t)kc * 64 + b) * 236 + o];
        out[b * 236 + o] = acc;
    }
}

// ---------------------------------------------------------------------------
extern "C" void kernel_launch(void* const* d_in, const int* in_sizes, int n_in,
                              void* d_out, int out_size, void* d_ws, size_t ws_size,
                              hipStream_t stream) {
    const float* p   = (const float*)d_in[0];
    const float* sf  = (const float*)d_in[1];
    const float* w0  = (const float*)d_in[2];
    const float* b0  = (const float*)d_in[3];
    const float* w1  = (const float*)d_in[4];
    const float* b1  = (const float*)d_in[5];
    const float* w2  = (const float*)d_in[6];
    const float* b2  = (const float*)d_in[7];
    const float* fcw = (const float*)d_in[8];
    const float* fcb = (const float*)d_in[9];
    float* out = (float*)d_out;

    char* ws = (char*)d_ws;
    // ws layout (bytes):
    unsigned int*   featB = (unsigned int*)(ws);               // [64][32][4][512] u32 16,777,216
    float*          y2f   = (float*)(ws + 16777216);           //     640,000
    float*          fcwT  = (float*)(ws + 17417216);           //   2,360,000
    float*          part  = (float*)(ws + 19777216);           //     483,328
    unsigned short* w0f   = (unsigned short*)(ws + 20260544);  //      65,536
    unsigned short* w1f   = (unsigned short*)(ws + 20326080);  //      49,152
    unsigned short* w2f   = (unsigned short*)(ws + 20375232);  //      10,240
                                                               // end: 20,385,472

    k_gp<<<TOTAL_BLKS, 256, 0, stream>>>(sf, p, w0, w1, w2, fcw,
                                         featB, w0f, w1f, w2f, fcwT);
    k_mlp<<<dim3(8, BB), 512, 0, stream>>>(featB, w0f, w1f, w2f,
                                           b0, b1, b2, y2f);
    k_fc1<<<512, 256, 0, stream>>>(y2f, fcwT, part);
    k_fc2<<<BB, 256, 0, stream>>>(part, fcb, out);
}

// Round 21
// 79.445 us; speedup vs baseline: 1.0704x; 1.0704x over previous
//
#include <hip/hip_runtime.h>
#include <hip/hip_bf16.h>

// Problem constants
#define BB 64
#define NN 500
#define CC 256
#define HH 64
#define WW 64
#define HWSZ 4096
#define NPTS 32000
#define NPAD 512

typedef __attribute__((ext_vector_type(4))) short s4v;
typedef __attribute__((ext_vector_type(8))) short s8v;
typedef __attribute__((ext_vector_type(4))) float f4v;
typedef __attribute__((ext_vector_type(4))) int i4v;

// RNE round f32 -> bf16 (ushort)
__device__ __forceinline__ unsigned short bfround(float f) {
    unsigned u = __builtin_bit_cast(unsigned, f);
    return (unsigned short)((u + 0x7FFFu + ((u >> 16) & 1u)) >> 16);
}

// ---------------------------------------------------------------------------
// K1: gather (3-buffer pipelined) + weight-frag pack + TILED fcwT transpose.
// (r19-identical — best verified configuration, 79.6 us total.)
//  blk < 2048:               gather: (batch, 8-ch chunk), 512 thr, 3x16KB
//                            LDS ring, DMA 2 periods ahead, vmcnt(4) steady.
//  2048 <= blk < 2048+122:   weight fragment pack (r7-verified k-labeling)
//  blk >= 2048+122:          fcwT tiled transpose (coalesced both sides)
// ---------------------------------------------------------------------------
#define GATHER_BLKS 2048
#define NCHB 8
#define NBUF 3
#define W0F_N 32768   // 8 Mt * 8 s * 512
#define W1F_N 24576   // 4 Mt * 12 s * 512
#define W2F_N 5120    // 1 Mt * 10 s * 512
#define PACK_N (W0F_N + W1F_N + W2F_N)
#define PACK_BLKS ((PACK_N + 511) / 512)      // 122
#define TR_BLKS (40 * 4)                      // 2500/64 x 236/64 tiles
#define TOTAL_BLKS (GATHER_BLKS + PACK_BLKS + TR_BLKS)

__global__ __launch_bounds__(512) void k_gp(const float* __restrict__ sfeat,
                                            const float* __restrict__ pts,
                                            const float* __restrict__ w0,
                                            const float* __restrict__ w1,
                                            const float* __restrict__ w2,
                                            const float* __restrict__ fcw,
                                            unsigned int* __restrict__ featB,
                                            unsigned short* __restrict__ w0f,
                                            unsigned short* __restrict__ w1f,
                                            unsigned short* __restrict__ w2f,
                                            float* __restrict__ fcwT) {
    __shared__ float im[NBUF][HWSZ];   // 48 KB -> 3 blocks/CU
    const int blk = blockIdx.x;
    const int tid = threadIdx.x;

    if (blk >= GATHER_BLKS + PACK_BLKS) {
        // ---- fcwT tiled transpose: tile 64k x 64o, LDS reuses im ----
        float (*tile)[65] = (float(*)[65])im;  // 64*65*4 = 16.6 KB < 48 KB
        const int tb = blk - (GATHER_BLKS + PACK_BLKS);
        const int kt = tb % 40, ot = tb / 40;
        const int k0 = kt * 64, o0 = ot * 64;
        for (int i = tid; i < 64 * 64; i += 512) {
            int oo = i >> 6, kk = i & 63;                  // lane-major kk
            int o = o0 + oo, k = k0 + kk;
            tile[oo][kk] = (o < 236 && k < 2500) ? fcw[(size_t)o * 2500 + k] : 0.f;
        }
        __syncthreads();
        for (int i = tid; i < 64 * 64; i += 512) {
            int kk = i >> 6, oo = i & 63;                  // lane-major oo
            int o = o0 + oo, k = k0 + kk;
            if (o < 236 && k < 2500) fcwT[(size_t)k * 236 + o] = tile[oo][kk];
        }
        return;
    }

    if (blk >= GATHER_BLKS) {
        // ---- weight-frag pack ----
        int i = (blk - GATHER_BLKS) * 512 + tid;
        if (i < W0F_N) {
            int j = i & 7, ll = (i >> 3) & 63, s = (i >> 9) & 7, m = i >> 12;
            int row = m * 16 + (ll & 15), k = s * 32 + (ll >> 4) * 8 + j;
            w0f[i] = bfround(w0[row * 256 + k]);
        } else if (i < W0F_N + W1F_N) {
            int d = i - W0F_N;
            int j = d & 7, ll = (d >> 3) & 63, rest = d >> 9;
            int s = rest % 12, m = rest / 12;
            int row = m * 16 + (ll & 15), k = s * 32 + (ll >> 4) * 8 + j;
            w1f[d] = bfround(w1[row * 384 + k]);
        } else if (i < PACK_N) {
            int d = i - (W0F_N + W1F_N);
            int j = d & 7, ll = (d >> 3) & 63, s = d >> 9;
            int row = ll & 15, k = s * 32 + (ll >> 4) * 8 + j;
            float v = (row < 5) ? w2[row * 320 + k] : 0.f;
            w2f[d] = bfround(v);
        }
        return;
    }

    // ---- gather path ----
    const int b     = blk >> 5;          // 32 chunks per batch
    const int chunk = blk & 31;
    const int ch0   = chunk * NCHB;
    const int n     = tid;

    int4 id = make_int4(0, 0, 0, 0);
    float4 wt = make_float4(0.f, 0.f, 0.f, 0.f);
    if (n < NN) {
        float x = (pts[((size_t)b * NN + n) * 2 + 0] + 1.f) * 0.5f * (float)(WW - 1);
        float y = (pts[((size_t)b * NN + n) * 2 + 1] + 1.f) * 0.5f * (float)(HH - 1);
        float x0f = floorf(x), y0f = floorf(y);
        float x1f = x0f + 1.f, y1f = y0f + 1.f;
        float wx1 = x - x0f, wx0 = 1.f - wx1;
        float wy1 = y - y0f, wy0 = 1.f - wy1;
        float mx0 = (x0f >= 0.f && x0f <= (float)(WW - 1)) ? 1.f : 0.f;
        float mx1 = (x1f >= 0.f && x1f <= (float)(WW - 1)) ? 1.f : 0.f;
        float my0 = (y0f >= 0.f && y0f <= (float)(HH - 1)) ? 1.f : 0.f;
        float my1 = (y1f >= 0.f && y1f <= (float)(HH - 1)) ? 1.f : 0.f;
        int x0 = (int)fminf(fmaxf(x0f, 0.f), (float)(WW - 1));
        int x1 = (int)fminf(fmaxf(x1f, 0.f), (float)(WW - 1));
        int y0 = (int)fminf(fmaxf(y0f, 0.f), (float)(HH - 1));
        int y1 = (int)fminf(fmaxf(y1f, 0.f), (float)(HH - 1));
        id = make_int4(y0 * WW + x0, y0 * WW + x1, y1 * WW + x0, y1 * WW + x1);
        wt = make_float4(wx0 * wy0 * mx0 * my0, wx1 * wy0 * mx1 * my0,
                         wx0 * wy1 * mx0 * my1, wx1 * wy1 * mx1 * my1);
    }

    const float4* src = (const float4*)(sfeat + ((size_t)b * CC + ch0) * HWSZ);

#define ISSUE_CH(T, BUF)                                                      \
    {                                                                         \
        const float4* s2 = src + (size_t)(T) * (HWSZ / 4);                    \
        float4* dst = (float4*)im[BUF];                                       \
        _Pragma("unroll")                                                     \
        for (int it = 0; it < 2; it++) {                                      \
            int j = it * 512 + tid;                                           \
            __builtin_amdgcn_global_load_lds(                                 \
                (const __attribute__((address_space(1))) void*)(s2 + j),      \
                (__attribute__((address_space(3))) void*)(dst + j),           \
                16, 0, 0);                                                    \
        }                                                                     \
    }

    ISSUE_CH(0, 0);
    ISSUE_CH(1, 1);

    unsigned short hprev = 0;
    for (int t = 0; t < NCHB; t++) {
        if (t + 2 < NCHB) {
            ISSUE_CH(t + 2, (t + 2) % 3);
            asm volatile("s_waitcnt vmcnt(4)" ::: "memory");
        } else if (t + 1 < NCHB) {
            asm volatile("s_waitcnt vmcnt(2)" ::: "memory");
        } else {
            asm volatile("s_waitcnt vmcnt(0)" ::: "memory");
        }
        asm volatile("s_barrier" ::: "memory");

        if (n < NN) {
            const float* L = im[t % 3];
            float r = wt.x * L[id.x] + wt.y * L[id.y] + wt.z * L[id.z] + wt.w * L[id.w];
            unsigned short h = bfround(r);
            if (t & 1) {
                unsigned int v = (unsigned int)hprev | ((unsigned int)h << 16);
                featB[(((size_t)b * 32 + chunk) * 4 + (t >> 1)) * 512 + n] = v;
            } else {
                hprev = h;
            }
        }
        if (t + 1 < NCHB)
            asm volatile("s_barrier" ::: "memory");
    }
#undef ISSUE_CH
}

// ---------------------------------------------------------------------------
// K2: plain-bf16 MFMA fused MLP, TILE=64 points/block (r19-identical).
// 8 waves: nt=w&3 (col group), mh=w>>2 (row half).
// ---------------------------------------------------------------------------
#define K1_S 136
#define K2_S 72

__device__ __forceinline__ s8v mkfrag(const unsigned short* p) {
    return *(const s8v*)p;
}

__global__ __launch_bounds__(512, 4) void k_mlp(const unsigned int* __restrict__ featB,
                                                const unsigned short* __restrict__ w0f,
                                                const unsigned short* __restrict__ w1f,
                                                const unsigned short* __restrict__ w2f,
                                                const float* __restrict__ b0,
                                                const float* __restrict__ b1,
                                                const float* __restrict__ b2,
                                                float* __restrict__ y2f) {
    __shared__ unsigned short c1B[64 * K1_S];
    __shared__ unsigned short c2B[64 * K2_S];   // total 26,624 B

    const int b   = blockIdx.y;
    const int n0  = blockIdx.x * 64;
    const int tid = threadIdx.x;
    const int w   = tid >> 6, l = tid & 63;
    const int nt  = w & 3, mh = w >> 2;
    const int lo16 = l & 15, hi = l >> 4;
    const int c = nt * 16 + lo16;          // point column 0..63

    // ---- B-fragments: 32 x 4B coalesced loads ----
    s8v bhs[8];
    const unsigned int* fb = featB + (size_t)b * (32 * 4 * 512) + (n0 + c);
#pragma unroll
    for (int s = 0; s < 8; s++) {
        const int kg = s * 4 + hi;
        i4v hx;
#pragma unroll
        for (int t = 0; t < 4; t++)
            hx[t] = (int)fb[(size_t)(kg * 4 + t) * 512];
        bhs[s] = __builtin_bit_cast(s8v, hx);
    }

    // ---- layer 0: 128 outs (8 Mt), K=256; wave does Mt = mh*4 + q ----
    f4v acc[4];
#pragma unroll
    for (int q = 0; q < 4; q++) acc[q] = (f4v){0.f, 0.f, 0.f, 0.f};
#pragma unroll
    for (int s = 0; s < 8; s++) {
#pragma unroll
        for (int q = 0; q < 4; q++) {
            const s8v a = mkfrag(w0f + ((size_t)((mh * 4 + q) * 8 + s) * 64 + l) * 8);
            acc[q] = __builtin_amdgcn_mfma_f32_16x16x32_bf16(a, bhs[s], acc[q], 0, 0, 0);
        }
    }
#pragma unroll
    for (int q = 0; q < 4; q++) {
#pragma unroll
        for (int r = 0; r < 4; r++) {
            int ch = (mh * 4 + q) * 16 + hi * 4 + r;
            float v = acc[q][r] + b0[ch];
            v = v > 0.f ? v : 0.01f * v;
            c1B[c * K1_S + ch] = bfround(v);
        }
    }
    __syncthreads();

    // ---- layer 1: 64 outs (4 Mt), K=128(c1)+256(feat); Mt = mh*2 + q ----
    f4v accA[2];
#pragma unroll
    for (int q = 0; q < 2; q++) accA[q] = (f4v){0.f, 0.f, 0.f, 0.f};
#pragma unroll
    for (int s = 0; s < 4; s++) {
        const s8v bh = *(const s8v*)&c1B[c * K1_S + s * 32 + hi * 8];
#pragma unroll
        for (int q = 0; q < 2; q++) {
            const s8v a = mkfrag(w1f + ((size_t)((mh * 2 + q) * 12 + s) * 64 + l) * 8);
            accA[q] = __builtin_amdgcn_mfma_f32_16x16x32_bf16(a, bh, accA[q], 0, 0, 0);
        }
    }
#pragma unroll
    for (int s = 4; s < 12; s++) {
#pragma unroll
        for (int q = 0; q < 2; q++) {
            const s8v a = mkfrag(w1f + ((size_t)((mh * 2 + q) * 12 + s) * 64 + l) * 8);
            accA[q] = __builtin_amdgcn_mfma_f32_16x16x32_bf16(a, bhs[s - 4], accA[q], 0, 0, 0);
        }
    }
#pragma unroll
    for (int q = 0; q < 2; q++) {
#pragma unroll
        for (int r = 0; r < 4; r++) {
            int ch = (mh * 2 + q) * 16 + hi * 4 + r;
            float v = accA[q][r] + b1[ch];
            v = v > 0.f ? v : 0.01f * v;
            c2B[c * K2_S + ch] = bfround(v);
        }
    }
    __syncthreads();

    // ---- layer 2: 5 outs (1 Mt), K=64(c2)+256(feat); waves mh==0 ----
    if (mh == 0) {
        f4v acc2 = {0.f, 0.f, 0.f, 0.f};
#pragma unroll
        for (int s = 0; s < 2; s++) {
            const s8v bh = *(const s8v*)&c2B[c * K2_S + s * 32 + hi * 8];
            const s8v a  = mkfrag(w2f + ((size_t)s * 64 + l) * 8);
            acc2 = __builtin_amdgcn_mfma_f32_16x16x32_bf16(a, bh, acc2, 0, 0, 0);
        }
#pragma unroll
        for (int s = 2; s < 10; s++) {
            const s8v a = mkfrag(w2f + ((size_t)s * 64 + l) * 8);
            acc2 = __builtin_amdgcn_mfma_f32_16x16x32_bf16(a, bhs[s - 2], acc2, 0, 0, 0);
        }
#pragma unroll
        for (int r = 0; r < 4; r++) {
            int ch = hi * 4 + r;
            if (ch < 5) {
                float v = acc2[r] + b2[ch];
                v = fmaxf(v, 0.f);
                int n = n0 + c;
                if (n < NN) y2f[(size_t)b * 2500 + ch * NN + n] = v;
            }
        }
    }
}

// ---------------------------------------------------------------------------
// K3: FC two-stage (r19-identical). FC needs BOTH: k-split TLP AND coalesced
// weight reads (r10/r16 each violated one -> 170-200us).
// ---------------------------------------------------------------------------
__global__ __launch_bounds__(256) void k_fc1(const float* __restrict__ y2f,
                                             const float* __restrict__ fcwT,
                                             float* __restrict__ part) {
    __shared__ float ys[313];
    const int b  = blockIdx.x & 63;
    const int kc = blockIdx.x >> 6;
    const int start = kc * 312 + (kc < 4 ? kc : 4);
    const int len   = (kc < 4) ? 313 : 312;
    const float* yb = y2f + (size_t)b * 2500 + start;
    for (int j = threadIdx.x; j < len; j += 256) ys[j] = yb[j];
    __syncthreads();
    const int o = threadIdx.x;
    if (o < 236) {
        float acc = 0.f;
        const float* wp = fcwT + (size_t)start * 236 + o;
#pragma unroll 8
        for (int k = 0; k < len; k++) acc = fmaf(wp[(size_t)k * 236], ys[k], acc);
        part[((size_t)kc * 64 + b) * 236 + o] = acc;
    }
}

__global__ __launch_bounds__(256) void k_fc2(const float* __restrict__ part,
                                             const float* __restrict__ fcb,
                                             float* __restrict__ out) {
    const int b = blockIdx.x;
    const int o = threadIdx.x;
    if (o < 236) {
        float acc = fcb[o];
#pragma unroll
        for (int kc = 0; kc < 8; kc++) acc += part[((size_t)kc * 64 + b) * 236 + o];
        out[b * 236 + o] = acc;
    }
}

// ---------------------------------------------------------------------------
extern "C" void kernel_launch(void* const* d_in, const int* in_sizes, int n_in,
                              void* d_out, int out_size, void* d_ws, size_t ws_size,
                              hipStream_t stream) {
    const float* p   = (const float*)d_in[0];
    const float* sf  = (const float*)d_in[1];
    const float* w0  = (const float*)d_in[2];
    const float* b0  = (const float*)d_in[3];
    const float* w1  = (const float*)d_in[4];
    const float* b1  = (const float*)d_in[5];
    const float* w2  = (const float*)d_in[6];
    const float* b2  = (const float*)d_in[7];
    const float* fcw = (const float*)d_in[8];
    const float* fcb = (const float*)d_in[9];
    float* out = (float*)d_out;

    char* ws = (char*)d_ws;
    // ws layout (bytes):
    unsigned int*   featB = (unsigned int*)(ws);               // [64][32][4][512] u32 16,777,216
    float*          y2f   = (float*)(ws + 16777216);           //     640,000
    float*          fcwT  = (float*)(ws + 17417216);           //   2,360,000
    float*          part  = (float*)(ws + 19777216);           //     483,328
    unsigned short* w0f   = (unsigned short*)(ws + 20260544);  //      65,536
    unsigned short* w1f   = (unsigned short*)(ws + 20326080);  //      49,152
    unsigned short* w2f   = (unsigned short*)(ws + 20375232);  //      10,240
                                                               // end: 20,385,472

    k_gp<<<TOTAL_BLKS, 512, 0, stream>>>(sf, p, w0, w1, w2, fcw,
                                         featB, w0f, w1f, w2f, fcwT);
    k_mlp<<<dim3(8, BB), 512, 0, stream>>>(featB, w0f, w1f, w2f,
                                           b0, b1, b2, y2f);
    k_fc1<<<512, 256, 0, stream>>>(y2f, fcwT, part);
    k_fc2<<<BB, 256, 0, stream>>>(part, fcb, out);
}